// Round 2
// baseline (10294.962 us; speedup 1.0000x reference)
//
#include <hip/hip_runtime.h>

typedef unsigned short u16;
typedef __attribute__((ext_vector_type(4))) float f32x4;
typedef __attribute__((ext_vector_type(2))) float f32x2;
typedef __attribute__((ext_vector_type(8))) short short8;

#define B_ 32
#define P_ 196
#define T_ 64
#define E_ 512
#define V_ 32000

__device__ __forceinline__ u16 f2bf(float x){
  unsigned int u = __float_as_uint(x);
  u += 0x7FFFu + ((u >> 16) & 1u);
  return (u16)(u >> 16);
}
__device__ __forceinline__ float bf2f(u16 x){
  return __uint_as_float(((unsigned int)x) << 16);
}
__device__ __forceinline__ float sigf(float x){ return 1.0f/(1.0f + __expf(-x)); }
__device__ __forceinline__ float tanhfast(float x){
  float e = __expf(-2.0f*fabsf(x));
  float t = (1.0f - e)/(1.0f + e);
  return x >= 0.0f ? t : -t;
}

// ---------- setup kernels ----------

__global__ __launch_bounds__(256) void k_cvt_bf16(const float* __restrict__ s,
                                                  u16* __restrict__ d, int n8){
  int i = blockIdx.x*256 + threadIdx.x;
  if (i >= n8) return;
  const f32x4* sp = (const f32x4*)(s + (size_t)i*8);
  f32x4 a = sp[0], b = sp[1];
  short8 v;
#pragma unroll
  for (int j=0;j<4;++j){ v[j] = (short)f2bf(a[j]); v[4+j] = (short)f2bf(b[j]); }
  *(short8*)(d + (size_t)i*8) = v;
}

// W_enc [512][512] (k-major rows) -> WT [a][k] bf16
__global__ __launch_bounds__(256) void k_wencT(const float* __restrict__ W, u16* __restrict__ WT){
  int tid = threadIdx.x;
  int kc = tid & 63, a = blockIdx.x*4 + (tid >> 6);
  short8 v;
#pragma unroll
  for (int j=0;j<8;++j) v[j] = (short)f2bf(W[(kc*8+j)*512 + a]);
  *(short8*)(WT + a*512 + kc*8) = v;
}

__global__ __launch_bounds__(256) void k_mean(const float* __restrict__ enc, float* __restrict__ mean){
  int b = blockIdx.x, tid = threadIdx.x;
  f32x2 acc; acc.x = 0.f; acc.y = 0.f;
  for (int p=0;p<P_;++p){
    f32x2 v = *(const f32x2*)(enc + ((size_t)(b*P_+p))*512 + tid*2);
    acc.x += v.x; acc.y += v.y;
  }
  acc.x *= (1.0f/196.0f); acc.y *= (1.0f/196.0f);
  *(f32x2*)(mean + b*512 + tid*2) = acc;
}

// h/c init
__global__ __launch_bounds__(256) void k_init_state(const float* __restrict__ mean,
    const float* __restrict__ Wh, const float* __restrict__ bh,
    const float* __restrict__ Wc, const float* __restrict__ bc,
    float* __restrict__ h0, float* __restrict__ h1,
    float* __restrict__ c0, float* __restrict__ c1){
  int bid = blockIdx.x;
  int which = bid >> 7, r = (bid >> 2) & 31, jg = bid & 3;
  const float* W = which ? Wc : Wh;
  const float* bb = which ? bc : bh;
  __shared__ float m[512];
  for (int i=threadIdx.x; i<512; i+=256) m[i] = mean[r*512 + i];
  __syncthreads();
  int j = jg*256 + threadIdx.x;
  float acc = bb[j];
  for (int e=0;e<512;++e) acc += m[e]*W[e*1024 + j];
  int l = r >> 4;
  int bb2 = ((r & 15) << 1) | (j >> 9);
  int hh = j & 511;
  float* dst = which ? (l ? c1 : c0) : (l ? h1 : h0);
  dst[bb2*512 + hh] = acc;
}

// ---------- bf16 GEMM: C[M][N] = A[M][512] * Bm[N][512]^T + bias ----------
// padded LDS stride 40 u16 (80B) to kill the 8-way read bank conflict.
#define LDAP 40
__global__ __launch_bounds__(256) void k_gemm_bf16(
    const u16* __restrict__ A, const u16* __restrict__ Bm,
    const float* __restrict__ bias, float* __restrict__ C, int N){
  __shared__ __align__(16) u16 As[128*LDAP];
  __shared__ __align__(16) u16 Bs[128*LDAP];
  int tid = threadIdx.x, l = tid & 63, w = tid >> 6;
  int m0 = blockIdx.x * 128, n0 = blockIdx.y * 128;
  int wm = w >> 1, wn = w & 1;
  f32x4 acc[4][4];
#pragma unroll
  for (int a=0;a<4;++a)
#pragma unroll
    for (int b=0;b<4;++b) acc[a][b] = (f32x4)0.0f;

  int srow = tid >> 2, schunk = tid & 3;
  const u16* gA = A + (size_t)(m0 + srow)*512 + schunk*8;
  const u16* gB = Bm + (size_t)(n0 + srow)*512 + schunk*8;
  int lr = l & 15, lk = (l >> 4) * 8;

  for (int k0 = 0; k0 < 512; k0 += 32){
    short8 va0 = *(const short8*)(gA + k0);
    short8 va1 = *(const short8*)(gA + (size_t)64*512 + k0);
    short8 vb0 = *(const short8*)(gB + k0);
    short8 vb1 = *(const short8*)(gB + (size_t)64*512 + k0);
    __syncthreads();
    *(short8*)(As + srow*LDAP + schunk*8) = va0;
    *(short8*)(As + (64+srow)*LDAP + schunk*8) = va1;
    *(short8*)(Bs + srow*LDAP + schunk*8) = vb0;
    *(short8*)(Bs + (64+srow)*LDAP + schunk*8) = vb1;
    __syncthreads();
    short8 af[4], bfv[4];
#pragma unroll
    for (int mt=0; mt<4; ++mt) af[mt]  = *(const short8*)(As + (wm*64 + mt*16 + lr)*LDAP + lk);
#pragma unroll
    for (int nt=0; nt<4; ++nt) bfv[nt] = *(const short8*)(Bs + (wn*64 + nt*16 + lr)*LDAP + lk);
#pragma unroll
    for (int mt=0; mt<4; ++mt)
#pragma unroll
      for (int nt=0; nt<4; ++nt)
        acc[mt][nt] = __builtin_amdgcn_mfma_f32_16x16x32_bf16(af[mt], bfv[nt], acc[mt][nt], 0, 0, 0);
  }
#pragma unroll
  for (int mt=0; mt<4; ++mt){
    int row = m0 + wm*64 + mt*16 + ((l >> 4) << 2);
#pragma unroll
    for (int nt=0; nt<4; ++nt){
      int col = n0 + wn*64 + nt*16 + (l & 15);
      float bv = bias[col];
#pragma unroll
      for (int j=0;j<4;++j)
        C[(size_t)(row + j)*N + col] = acc[mt][nt][j] + bv;
    }
  }
}

// ---------- per-step kernels ----------

// attention, one block per batch element. 256 threads = 4 waves.
// Also assembles Xcat=[emb|ctx|h0prev] and X1cat[512:1024]=h1prev.
__global__ __launch_bounds__(256) void k_attn(
    const float* __restrict__ h1buf, const float* __restrict__ h0buf,
    const u16* __restrict__ WdecBF, const float* __restrict__ bdec,
    const u16* __restrict__ encattBF, const float* __restrict__ Wfull,
    const float* __restrict__ bfull, const float* __restrict__ enc,
    const int* __restrict__ caps, int t, const float* __restrict__ embW,
    float* __restrict__ Xcat, float* __restrict__ X1cat){
  int b = blockIdx.x;
  int tid = threadIdx.x, l = tid & 63, w = tid >> 6;
  __shared__ float h1s[512];
  __shared__ float att2p[4][512];
  __shared__ float att2f[512];
  __shared__ float alph[224];
  __shared__ float partS[4];
  __shared__ float ctxp[4][512];
  __shared__ float Sinv_s;

  int cap = caps[b*T_ + t];
  for (int i=tid; i<512; i+=256){
    h1s[i] = h1buf[b*512 + i];
    Xcat[b*1536 + i] = embW[(size_t)cap*512 + i];
    Xcat[b*1536 + 1024 + i] = h0buf[b*512 + i];
    X1cat[b*1024 + 512 + i] = h1buf[b*512 + i];
  }
  __syncthreads();

  // att2 partial: wave w covers h in [w*128, w*128+128)
  {
    float acc[8];
#pragma unroll
    for (int j=0;j<8;++j) acc[j] = 0.f;
    const u16* Wp = WdecBF + (size_t)(w*128)*512 + l*8;
    for (int h=0; h<128; ++h){
      float hv = h1s[w*128 + h];
      short8 wv = *(const short8*)(Wp + (size_t)h*512);
#pragma unroll
      for (int j=0;j<8;++j) acc[j] += hv * bf2f((u16)wv[j]);
    }
#pragma unroll
    for (int j=0;j<8;++j) att2p[w][l*8+j] = acc[j];
  }
  __syncthreads();
  for (int a=tid; a<512; a+=256)
    att2f[a] = bdec[a] + att2p[0][a] + att2p[1][a] + att2p[2][a] + att2p[3][a];
  __syncthreads();

  // per-lane regs
  float a2[8], wf[8];
#pragma unroll
  for (int j=0;j<8;++j){ a2[j] = att2f[l*8+j]; wf[j] = Wfull[l*8+j]; }
  float bf0 = bfull[0];

  // e logits: wave per p
  for (int p=w; p<P_; p+=4){
    const u16* ep = encattBF + ((size_t)(b*P_ + p))*512 + l*8;
    short8 ev = *(const short8*)ep;
    float s = 0.f;
#pragma unroll
    for (int j=0;j<8;++j)
      s += fmaxf(bf2f((u16)ev[j]) + a2[j], 0.f) * wf[j];
#pragma unroll
    for (int o=32;o>=1;o>>=1) s += __shfl_xor(s, o);
    if (l == 0) alph[p] = s + bf0;
  }
  __syncthreads();
  // softmax (no max-sub; logits are O(1))
  {
    float v = 0.f;
    if (tid < P_){ v = __expf(alph[tid]); alph[tid] = v; }
    if (tid >= P_ && tid < 224) alph[tid] = 0.f;
#pragma unroll
    for (int o=32;o>=1;o>>=1) v += __shfl_xor(v, o);
    if (l == 0) partS[w] = v;
  }
  __syncthreads();
  if (tid == 0) Sinv_s = 1.0f/(partS[0]+partS[1]+partS[2]+partS[3]);

  // context partial: wave w covers p in [w*49, w*49+49)
  {
    float acc[8];
#pragma unroll
    for (int j=0;j<8;++j) acc[j] = 0.f;
    for (int i=0;i<49;++i){
      int p = w*49 + i;
      float wp = alph[p];
      const float* epp = enc + ((size_t)(b*P_ + p))*512 + l*8;
      f32x4 e0 = *(const f32x4*)epp;
      f32x4 e1 = *(const f32x4*)(epp+4);
#pragma unroll
      for (int j=0;j<4;++j){ acc[j] += wp*e0[j]; acc[4+j] += wp*e1[j]; }
    }
#pragma unroll
    for (int j=0;j<8;++j) ctxp[w][l*8+j] = acc[j];
  }
  __syncthreads();
  float sinv = Sinv_s;
  for (int i=tid; i<512; i+=256)
    Xcat[b*1536 + 512 + i] = (ctxp[0][i]+ctxp[1][i]+ctxp[2][i]+ctxp[3][i]) * sinv;
}

// LSTM layer 0: gates[32][2048] = Xcat[32][1536] @ [Wih0|Whh0]^T
// grid 128 (4 cells each), 512 threads: t = c4(2b)|kh(1b)|gp(1b)|b(5b)
__global__ __launch_bounds__(512) void k_lstm0(
    const float* __restrict__ Xcat,
    const float* __restrict__ Wih0, const float* __restrict__ Whh0,
    const float* __restrict__ bih0, const float* __restrict__ bhh0,
    float* __restrict__ h0buf, float* __restrict__ c0buf,
    float* __restrict__ X1cat){
  int t = threadIdx.x;
  int c4 = t >> 7, kh = (t >> 6) & 1, gp = (t >> 5) & 1, b = t & 31;
  int cell = blockIdx.x*4 + c4;
  int r0 = (gp ? 1024 : 0) + cell;   // gp0: i(r),f(r+512); gp1: g(r),o(r+512)
  int r1 = r0 + 512;
  const float* Xb = Xcat + b*1536;
  f32x4 a0 = (f32x4)0.0f, a1 = (f32x4)0.0f;
  if (kh == 0){
    const float* w0 = Wih0 + (size_t)r0*1024;
    const float* w1 = Wih0 + (size_t)r1*1024;
#pragma unroll 4
    for (int k=0;k<768;k+=4){
      f32x4 x = *(const f32x4*)(Xb + k);
      f32x4 p = *(const f32x4*)(w0 + k);
      f32x4 q = *(const f32x4*)(w1 + k);
      a0 += x*p; a1 += x*q;
    }
  } else {
    const float* w0 = Wih0 + (size_t)r0*1024 + 768;
    const float* w1 = Wih0 + (size_t)r1*1024 + 768;
    const float* xb2 = Xb + 768;
#pragma unroll 4
    for (int k=0;k<256;k+=4){
      f32x4 x = *(const f32x4*)(xb2 + k);
      f32x4 p = *(const f32x4*)(w0 + k);
      f32x4 q = *(const f32x4*)(w1 + k);
      a0 += x*p; a1 += x*q;
    }
    const float* u0 = Whh0 + (size_t)r0*512;
    const float* u1 = Whh0 + (size_t)r1*512;
    const float* xb3 = Xb + 1024;
#pragma unroll 4
    for (int k=0;k<512;k+=4){
      f32x4 x = *(const f32x4*)(xb3 + k);
      f32x4 p = *(const f32x4*)(u0 + k);
      f32x4 q = *(const f32x4*)(u1 + k);
      a0 += x*p; a1 += x*q;
    }
  }
  __shared__ float gpart[512*2];
  gpart[t*2+0] = a0.x+a0.y+a0.z+a0.w;
  gpart[t*2+1] = a1.x+a1.y+a1.z+a1.w;
  __syncthreads();
  if (t < 128){
    int c4b = t >> 5, bb = t & 31;
    int cell2 = blockIdx.x*4 + c4b;
    int base = (c4b << 7) | bb;
    float gi = gpart[(base     )*2+0] + gpart[(base| 64)*2+0] + bih0[cell2]      + bhh0[cell2];
    float gf = gpart[(base     )*2+1] + gpart[(base| 64)*2+1] + bih0[512+cell2]  + bhh0[512+cell2];
    float gg = gpart[(base| 32)*2+0] + gpart[(base| 96)*2+0] + bih0[1024+cell2] + bhh0[1024+cell2];
    float go = gpart[(base| 32)*2+1] + gpart[(base| 96)*2+1] + bih0[1536+cell2] + bhh0[1536+cell2];
    float cp = c0buf[bb*512 + cell2];
    float cn = sigf(gf)*cp + sigf(gi)*tanhfast(gg);
    float hn = sigf(go)*tanhfast(cn);
    c0buf[bb*512 + cell2] = cn;
    h0buf[bb*512 + cell2] = hn;
    X1cat[bb*1024 + cell2] = hn;
  }
}

// LSTM layer 1: gates = X1cat[32][1024] @ [Wih1|Whh1]^T ; also h1_all bf16 store
__global__ __launch_bounds__(512) void k_lstm1(
    const float* __restrict__ X1cat,
    const float* __restrict__ Wih1, const float* __restrict__ Whh1,
    const float* __restrict__ bih1, const float* __restrict__ bhh1,
    float* __restrict__ h1buf, float* __restrict__ c1buf,
    u16* __restrict__ h1_all, int t_step){
  int t = threadIdx.x;
  int c4 = t >> 7, kh = (t >> 6) & 1, gp = (t >> 5) & 1, b = t & 31;
  int cell = blockIdx.x*4 + c4;
  int r0 = (gp ? 1024 : 0) + cell;
  int r1 = r0 + 512;
  const float* Xb = X1cat + b*1024;
  f32x4 a0 = (f32x4)0.0f, a1 = (f32x4)0.0f;
  if (kh == 0){
    const float* w0 = Wih1 + (size_t)r0*512;
    const float* w1 = Wih1 + (size_t)r1*512;
#pragma unroll 4
    for (int k=0;k<512;k+=4){
      f32x4 x = *(const f32x4*)(Xb + k);
      f32x4 p = *(const f32x4*)(w0 + k);
      f32x4 q = *(const f32x4*)(w1 + k);
      a0 += x*p; a1 += x*q;
    }
  } else {
    const float* u0 = Whh1 + (size_t)r0*512;
    const float* u1 = Whh1 + (size_t)r1*512;
    const float* xb2 = Xb + 512;
#pragma unroll 4
    for (int k=0;k<512;k+=4){
      f32x4 x = *(const f32x4*)(xb2 + k);
      f32x4 p = *(const f32x4*)(u0 + k);
      f32x4 q = *(const f32x4*)(u1 + k);
      a0 += x*p; a1 += x*q;
    }
  }
  __shared__ float gpart[512*2];
  gpart[t*2+0] = a0.x+a0.y+a0.z+a0.w;
  gpart[t*2+1] = a1.x+a1.y+a1.z+a1.w;
  __syncthreads();
  if (t < 128){
    int c4b = t >> 5, bb = t & 31;
    int cell2 = blockIdx.x*4 + c4b;
    int base = (c4b << 7) | bb;
    float gi = gpart[(base     )*2+0] + gpart[(base| 64)*2+0] + bih1[cell2]      + bhh1[cell2];
    float gf = gpart[(base     )*2+1] + gpart[(base| 64)*2+1] + bih1[512+cell2]  + bhh1[512+cell2];
    float gg = gpart[(base| 32)*2+0] + gpart[(base| 96)*2+0] + bih1[1024+cell2] + bhh1[1024+cell2];
    float go = gpart[(base| 32)*2+1] + gpart[(base| 96)*2+1] + bih1[1536+cell2] + bhh1[1536+cell2];
    float cp = c1buf[bb*512 + cell2];
    float cn = sigf(gf)*cp + sigf(gi)*tanhfast(gg);
    float hn = sigf(go)*tanhfast(cn);
    c1buf[bb*512 + cell2] = cn;
    h1buf[bb*512 + cell2] = hn;
    h1_all[((size_t)(bb*T_ + t_step))*512 + cell2] = f2bf(hn);
  }
}

// ---------- host ----------

extern "C" void kernel_launch(void* const* d_in, const int* in_sizes, int n_in,
                              void* d_out, int out_size, void* d_ws, size_t ws_size,
                              hipStream_t stream){
  const float* enc   = (const float*)d_in[0];
  const int*   caps  = (const int*)d_in[1];
  const float* embW  = (const float*)d_in[2];
  const float* fc_b  = (const float*)d_in[3];
  const float* Wenc  = (const float*)d_in[4];
  const float* benc  = (const float*)d_in[5];
  const float* Wdec  = (const float*)d_in[6];
  const float* bdec  = (const float*)d_in[7];
  const float* Wfull = (const float*)d_in[8];
  const float* bfull = (const float*)d_in[9];
  const float* Wih0  = (const float*)d_in[10];
  const float* Whh0  = (const float*)d_in[11];
  const float* bih0  = (const float*)d_in[12];
  const float* bhh0  = (const float*)d_in[13];
  const float* Wih1  = (const float*)d_in[14];
  const float* Whh1  = (const float*)d_in[15];
  const float* bih1  = (const float*)d_in[16];
  const float* bhh1  = (const float*)d_in[17];
  const float* Winh  = (const float*)d_in[18];
  const float* binh  = (const float*)d_in[19];
  const float* Winc  = (const float*)d_in[20];
  const float* binc  = (const float*)d_in[21];
  float* out = (float*)d_out;

  char* wsp = (char*)d_ws;
  size_t off = 0;
  auto alloc = [&](size_t bytes)->char*{
    char* p = wsp + off;
    off += (bytes + 255) & ~(size_t)255;
    return p;
  };
  u16*   A_enc    = (u16*)  alloc((size_t)6272*512*2);
  u16*   emb_bf   = (u16*)  alloc((size_t)V_*512*2);
  u16*   WencT    = (u16*)  alloc((size_t)512*512*2);
  u16*   WdecBF   = (u16*)  alloc((size_t)512*512*2);
  float* encatt   = (float*)alloc((size_t)6272*512*4);
  u16*   encattBF = (u16*)  alloc((size_t)6272*512*2);
  float* meanb    = (float*)alloc((size_t)32*512*4);
  float* h0buf    = (float*)alloc(32*512*4);
  float* h1buf    = (float*)alloc(32*512*4);
  float* c0buf    = (float*)alloc(32*512*4);
  float* c1buf    = (float*)alloc(32*512*4);
  float* Xcat     = (float*)alloc((size_t)32*1536*4);
  float* X1cat    = (float*)alloc((size_t)32*1024*4);
  u16*   h1_all   = (u16*)  alloc((size_t)2048*512*2);
  if (off > ws_size) return;

  // setup
  k_cvt_bf16<<<1568, 256, 0, stream>>>(enc, A_enc, 401408);
  k_cvt_bf16<<<8000, 256, 0, stream>>>(embW, emb_bf, 2048000);
  k_cvt_bf16<<<128, 256, 0, stream>>>(Wdec, WdecBF, 32768);
  k_wencT   <<<128, 256, 0, stream>>>(Wenc, WencT);
  k_mean    <<<32, 256, 0, stream>>>(enc, meanb);
  k_init_state<<<256, 256, 0, stream>>>(meanb, Winh, binh, Winc, binc,
                                        h0buf, h1buf, c0buf, c1buf);
  // enc_att = encoder_out @ W_enc + b_enc (f32), then bf16 copy
  k_gemm_bf16<<<dim3(49, 4), 256, 0, stream>>>(A_enc, WencT, benc, encatt, 512);
  k_cvt_bf16<<<1568, 256, 0, stream>>>(encatt, encattBF, 401408);

  // recurrence
  for (int t=0; t<T_; ++t){
    k_attn <<<32, 256, 0, stream>>>(h1buf, h0buf, WdecBF, bdec, encattBF,
                                    Wfull, bfull, enc, caps, t, embW,
                                    Xcat, X1cat);
    k_lstm0<<<128, 512, 0, stream>>>(Xcat, Wih0, Whh0, bih0, bhh0,
                                     h0buf, c0buf, X1cat);
    k_lstm1<<<128, 512, 0, stream>>>(X1cat, Wih1, Whh1, bih1, bhh1,
                                     h1buf, c1buf, h1_all, t);
  }

  // deferred tied-weight projection: out[2048][32000] = h1_all @ emb_W^T + fc_b
  k_gemm_bf16<<<dim3(16, 250), 256, 0, stream>>>(h1_all, emb_bf, fc_b, out, V_);
}